// Round 18
// baseline (119.313 us; speedup 1.0000x reference)
//
#include <hip/hip_runtime.h>

#define NF 64     // IN == HID
#define OF 32     // OUT

#define NPB 512        // nodes per bucket (power of 2)
#define NPB_SHIFT 9
#define BCAP 12288     // max staged edges per bucket (mean 8192)
#define BIN_CHUNK 4096 // edges per binning block (256 thr x 16)

typedef unsigned int uint;
typedef unsigned short ushort;
typedef __attribute__((ext_vector_type(8))) short bf16x8;
typedef __attribute__((ext_vector_type(4))) float f32x4;

// ---------------- bf16 helpers ----------------

__device__ __forceinline__ ushort f2bf(float f) {
    uint u = __float_as_uint(f);
    uint r = (u + 0x7fffu + ((u >> 16) & 1u)) >> 16;   // RNE
    return (ushort)r;
}
__device__ __forceinline__ float bf2f(ushort b) { return __uint_as_float(((uint)b) << 16); }
__device__ __forceinline__ float blo(uint u) { return __uint_as_float(u << 16); }
__device__ __forceinline__ float bhi(uint u) { return __uint_as_float(u & 0xffff0000u); }

// ---------------- zw: zero gcur + transposed bf16 weight prep (tiny, before binning) ----

__global__ void zw_kernel(const float* __restrict__ Ws1, const float* __restrict__ Wn1,
                          const float* __restrict__ Ws2, const float* __restrict__ Wn2,
                          ushort* __restrict__ wt1, ushort* __restrict__ wt2,
                          int* __restrict__ gcur) {
    int i = blockIdx.x * blockDim.x + threadIdx.x;
    if (blockIdx.x == 0) gcur[threadIdx.x] = 0;
    if (i < NF * 128) {        // wt1: 64 cols x 128 k
        int c = i >> 7, k = i & 127;
        float v = (k < 64) ? Ws1[k * NF + c] : Wn1[(k - 64) * NF + c];
        wt1[i] = f2bf(v);
    }
    if (i < OF * 128) {        // wt2: 32 cols x 128 k (k<64: Ws2, k>=64: Wn2)
        int c = i >> 7, k = i & 127;
        float v = (k < 64) ? Ws2[k * OF + c] : Wn2[(k - 64) * OF + c];
        wt2[i] = f2bf(v);
    }
}

// ---------------- convbin: convert (x->bf16) || binning (LDS counting-sort) ----------------
// Independent phases overlapped in one dispatch: blocks [0,cblocks) convert,
// blocks [cblocks, cblocks+bin_blocks) bin. Branch is blockIdx-uniform.

__global__ __launch_bounds__(256) void convbin_kernel(
        const float* __restrict__ x, ushort* __restrict__ xb, int n4, int cblocks,
        const int* __restrict__ src, const int* __restrict__ dst, int n_edges,
        int* __restrict__ gcur, uint* __restrict__ stage) {
    __shared__ int hist[256];
    __shared__ int lofs[256];
    __shared__ int gbase[256];
    __shared__ int lrank[256];
    __shared__ uint lsorted[BIN_CHUNK];
    __shared__ unsigned char lbkt[BIN_CHUNK];

    if ((int)blockIdx.x < cblocks) {
        int i = blockIdx.x * 256 + threadIdx.x;
        if (i < n4) {
            float4 v = *(const float4*)(x + (size_t)i * 4);
            ushort4 o;
            o.x = f2bf(v.x); o.y = f2bf(v.y); o.z = f2bf(v.z); o.w = f2bf(v.w);
            *(ushort4*)(xb + (size_t)i * 4) = o;
        }
        return;
    }

    int t = threadIdx.x;
    hist[t] = 0;
    lrank[t] = 0;
    __syncthreads();

    int e0 = ((int)blockIdx.x - cblocks) * BIN_CHUNK;
    int base_e = e0 + t * 16;
    int nloc = min(16, max(0, n_edges - base_e));

    uint es[16], ed[16];
    if (nloc == 16) {
#pragma unroll
        for (int q = 0; q < 4; q++) {
            uint4 s4 = *(const uint4*)(src + base_e + q * 4);
            uint4 d4 = *(const uint4*)(dst + base_e + q * 4);
            es[q * 4 + 0] = s4.x; es[q * 4 + 1] = s4.y; es[q * 4 + 2] = s4.z; es[q * 4 + 3] = s4.w;
            ed[q * 4 + 0] = d4.x; ed[q * 4 + 1] = d4.y; ed[q * 4 + 2] = d4.z; ed[q * 4 + 3] = d4.w;
        }
    } else {
        for (int j = 0; j < nloc; j++) {
            es[j] = (uint)src[base_e + j];
            ed[j] = (uint)dst[base_e + j];
        }
    }

    for (int j = 0; j < nloc; j++)
        atomicAdd(&hist[ed[j] >> NPB_SHIFT], 1);
    __syncthreads();

    int hv = hist[t];
    lofs[t] = hv;
    __syncthreads();
    for (int off = 1; off < 256; off <<= 1) {
        int u = (t >= off) ? lofs[t - off] : 0;
        __syncthreads();
        lofs[t] += u;
        __syncthreads();
    }
    int incl = lofs[t];
    __syncthreads();
    lofs[t] = incl - hv;   // exclusive
    if (hv > 0) gbase[t] = atomicAdd(&gcur[t], hv);
    __syncthreads();

    for (int j = 0; j < nloc; j++) {
        int b = ed[j] >> NPB_SHIFT;
        int r = atomicAdd(&lrank[b], 1);
        int pos = lofs[b] + r;
        lsorted[pos] = ((ed[j] & (NPB - 1)) << 17) | es[j];
        lbkt[pos] = (unsigned char)b;
    }
    __syncthreads();

    int bcnt = min(BIN_CHUNK, n_edges - e0);
    for (int i = t; i < bcnt; i += 256) {
        int b = lbkt[i];
        int pos = gbase[b] + (i - lofs[b]);
        if (pos < BCAP) stage[(size_t)b * BCAP + pos] = lsorted[i];
    }
}

// build: one block per bucket. Inline exclusive scan of bucket counts (nb<=256),
// then per-node counts + scan in LDS -> row_ptr; scatter srcs in LDS; stream out.
__global__ __launch_bounds__(256) void build_kernel(
        const uint* __restrict__ stage, const int* __restrict__ gcnt,
        int* __restrict__ row_ptr, int* __restrict__ csr, int n, int nb) {
    __shared__ int bsc[256];
    __shared__ int ncnt[NPB];
    __shared__ int lcur[NPB];
    __shared__ int psum[256];
    __shared__ int lcsr[BCAP];

    int b = blockIdx.x;
    int t = threadIdx.x;

    bsc[t] = (t < nb) ? gcnt[t] : 0;
    __syncthreads();
    for (int off = 1; off < 256; off <<= 1) {
        int u = (t >= off) ? bsc[t - off] : 0;
        __syncthreads();
        bsc[t] += u;
        __syncthreads();
    }
    int gbase = (b == 0) ? 0 : bsc[b - 1];

    int cnt = min(gcnt[b], BCAP);
    int node0 = b << NPB_SHIFT;
    const uint* st = stage + (size_t)b * BCAP;

    ncnt[t] = 0;
    ncnt[t + 256] = 0;
    __syncthreads();
    for (int i = t; i < cnt; i += 256)
        atomicAdd(&ncnt[st[i] >> 17], 1);
    __syncthreads();

    int a0 = ncnt[2 * t], a1 = ncnt[2 * t + 1];
    psum[t] = a0 + a1;
    __syncthreads();
    for (int off = 1; off < 256; off <<= 1) {
        int u = (t >= off) ? psum[t - off] : 0;
        __syncthreads();
        psum[t] += u;
        __syncthreads();
    }
    int excl = (t == 0) ? 0 : psum[t - 1];
    int off0 = excl, off1 = excl + a0;
    int g0 = node0 + 2 * t, g1 = node0 + 2 * t + 1;
    if (g0 < n) row_ptr[g0] = gbase + off0;
    if (g1 < n) row_ptr[g1] = gbase + off1;
    lcur[2 * t] = off0;
    lcur[2 * t + 1] = off1;
    __syncthreads();

    for (int i = t; i < cnt; i += 256) {
        uint p = st[i];
        int slot = atomicAdd(&lcur[p >> 17], 1);
        lcsr[slot] = (int)(p & 0x1FFFFu);
    }
    __syncthreads();
    for (int i = t; i < cnt; i += 256)
        csr[gbase + i] = lcsr[i];

    if (b == nb - 1 && t == 0) row_ptr[n] = bsc[nb - 1];
}

// ---------------- gather (layer 1): uint4 (16B/lane), full/tail split, 8-deep pipeline ----

__global__ __launch_bounds__(256) void gather_kernel(
        const ushort* __restrict__ feat,
        const int* __restrict__ row_ptr, const int* __restrict__ csr,
        ushort* __restrict__ agg, int n) {
    constexpr int LPG = NF / 8;
    constexpr int NPW = 64 / LPG;
    int lane = threadIdx.x & 63;
    int g = lane / LPG;
    int fo = (lane % LPG) * 8;
    int wave = blockIdx.x * 4 + (threadIdx.x >> 6);
    int stride = gridDim.x * 4 * NPW;

    for (int n0 = wave * NPW + g; n0 < n; n0 += stride) {
        int beg = row_ptr[n0], end = row_ptr[n0 + 1];
        int cnt = end - beg;
        int full = beg + (cnt & ~7);
        float a0 = 0.f, a1 = 0.f, a2 = 0.f, a3 = 0.f;
        float a4 = 0.f, a5 = 0.f, a6 = 0.f, a7 = 0.f;
        for (int o = beg; o < full; o += 8) {
            uint4 v[8];
#pragma unroll
            for (int j = 0; j < 8; j++)
                v[j] = *(const uint4*)(feat + (size_t)csr[o + j] * NF + fo);
#pragma unroll
            for (int j = 0; j < 8; j++) {
                a0 += blo(v[j].x); a1 += bhi(v[j].x);
                a2 += blo(v[j].y); a3 += bhi(v[j].y);
                a4 += blo(v[j].z); a5 += bhi(v[j].z);
                a6 += blo(v[j].w); a7 += bhi(v[j].w);
            }
        }
        if (full < end) {
            uint4 v[8];
#pragma unroll
            for (int j = 0; j < 8; j++) {
                int e = min(full + j, end - 1);
                v[j] = *(const uint4*)(feat + (size_t)csr[e] * NF + fo);
            }
#pragma unroll
            for (int j = 0; j < 8; j++) {
                bool ok = (full + j) < end;
                uint vx = ok ? v[j].x : 0u, vy = ok ? v[j].y : 0u;
                uint vz = ok ? v[j].z : 0u, vw = ok ? v[j].w : 0u;
                a0 += blo(vx); a1 += bhi(vx);
                a2 += blo(vy); a3 += bhi(vy);
                a4 += blo(vz); a5 += bhi(vz);
                a6 += blo(vw); a7 += bhi(vw);
            }
        }
        float inv = 1.0f / (float)max(cnt, 1);
        uint4 o4;
        o4.x = (uint)f2bf(a0 * inv) | ((uint)f2bf(a1 * inv) << 16);
        o4.y = (uint)f2bf(a2 * inv) | ((uint)f2bf(a3 * inv) << 16);
        o4.z = (uint)f2bf(a4 * inv) | ((uint)f2bf(a5 * inv) << 16);
        o4.w = (uint)f2bf(a6 * inv) | ((uint)f2bf(a7 * inv) << 16);
        *(uint4*)(agg + (size_t)n0 * NF + fo) = o4;
    }
}

// ---------------- gather_acc (layer 2): out[node] += mean(un2[src]) in fp32 ----------------

__global__ __launch_bounds__(256) void gather_acc_kernel(
        const ushort* __restrict__ un2,
        const int* __restrict__ row_ptr, const int* __restrict__ csr,
        float* __restrict__ out, int n) {
    constexpr int LPG = OF / 8;
    constexpr int NPW = 64 / LPG;
    int lane = threadIdx.x & 63;
    int g = lane / LPG;
    int fo = (lane % LPG) * 8;
    int wave = blockIdx.x * 4 + (threadIdx.x >> 6);
    int stride = gridDim.x * 4 * NPW;

    for (int n0 = wave * NPW + g; n0 < n; n0 += stride) {
        int beg = row_ptr[n0], end = row_ptr[n0 + 1];
        int cnt = end - beg;
        int full = beg + (cnt & ~7);
        float a0 = 0.f, a1 = 0.f, a2 = 0.f, a3 = 0.f;
        float a4 = 0.f, a5 = 0.f, a6 = 0.f, a7 = 0.f;
        for (int o = beg; o < full; o += 8) {
            uint4 v[8];
#pragma unroll
            for (int j = 0; j < 8; j++)
                v[j] = *(const uint4*)(un2 + (size_t)csr[o + j] * OF + fo);
#pragma unroll
            for (int j = 0; j < 8; j++) {
                a0 += blo(v[j].x); a1 += bhi(v[j].x);
                a2 += blo(v[j].y); a3 += bhi(v[j].y);
                a4 += blo(v[j].z); a5 += bhi(v[j].z);
                a6 += blo(v[j].w); a7 += bhi(v[j].w);
            }
        }
        if (full < end) {
            uint4 v[8];
#pragma unroll
            for (int j = 0; j < 8; j++) {
                int e = min(full + j, end - 1);
                v[j] = *(const uint4*)(un2 + (size_t)csr[e] * OF + fo);
            }
#pragma unroll
            for (int j = 0; j < 8; j++) {
                bool ok = (full + j) < end;
                uint vx = ok ? v[j].x : 0u, vy = ok ? v[j].y : 0u;
                uint vz = ok ? v[j].z : 0u, vw = ok ? v[j].w : 0u;
                a0 += blo(vx); a1 += bhi(vx);
                a2 += blo(vy); a3 += bhi(vy);
                a4 += blo(vz); a5 += bhi(vz);
                a6 += blo(vw); a7 += bhi(vw);
            }
        }
        float inv = 1.0f / (float)max(cnt, 1);
        float* op = out + (size_t)n0 * OF + fo;
        float4 o0 = *(const float4*)op;
        float4 o1 = *(const float4*)(op + 4);
        o0.x += a0 * inv; o0.y += a1 * inv; o0.z += a2 * inv; o0.w += a3 * inv;
        o1.x += a4 * inv; o1.y += a5 * inv; o1.z += a6 * inv; o1.w += a7 * inv;
        *(float4*)op = o0;
        *(float4*)(op + 4) = o1;
    }
}

// ---------------- gemm1_fused: hb = bf16(relu([xb|aggx]@Wt1^T + b1));
//                  un2 = bf16(hb@Wn2^T); out = hb@Ws2^T + b2 (fp32 self-term) ----------------
// SWAPPED operands: A = weights (row = out feature), B = node data (col = node).

__global__ __launch_bounds__(256) void gemm1_fused_kernel(
        const ushort* __restrict__ xb, const ushort* __restrict__ aggx,
        const ushort* __restrict__ wt1,  // [64][128]
        const ushort* __restrict__ wt2,  // [32][128] (k<64 = Ws2, k>=64 = Wn2)
        const float* __restrict__ b1,    // [64]
        const float* __restrict__ b2,    // [32]
        ushort* __restrict__ hb, ushort* __restrict__ un2,
        float* __restrict__ out, int n, int ntiles) {
    __shared__ char tiles[4][2048];
    int lane = threadIdx.x & 63;
    int wslot = threadIdx.x >> 6;
    char* tile = tiles[wslot];
    int col = lane & 15, kg = lane >> 4;
    int wid = blockIdx.x * 4 + wslot;
    int nw = gridDim.x * 4;
    int sw = (col & 7) << 4;

    bf16x8 wfrag[4][4];              // A = Wt1
#pragma unroll
    for (int ct = 0; ct < 4; ct++)
#pragma unroll
        for (int kt = 0; kt < 4; kt++)
            wfrag[ct][kt] = *(const bf16x8*)(wt1 + ((ct * 16 + col) * 128 + kt * 32 + kg * 8));
    bf16x8 wn2frag[2][2];            // A = Wn2 (k>=64 half of wt2)
    bf16x8 ws2frag[2][2];            // A = Ws2 (k<64 half of wt2)
#pragma unroll
    for (int c2 = 0; c2 < 2; c2++)
#pragma unroll
        for (int kt = 0; kt < 2; kt++) {
            wn2frag[c2][kt] = *(const bf16x8*)(wt2 + ((c2 * 16 + col) * 128 + 64 + kt * 32 + kg * 8));
            ws2frag[c2][kt] = *(const bf16x8*)(wt2 + ((c2 * 16 + col) * 128 + kt * 32 + kg * 8));
        }
    float4 bias4[4];
#pragma unroll
    for (int ct = 0; ct < 4; ct++) bias4[ct] = *(const float4*)(b1 + ct * 16 + kg * 4);
    float4 bias2_4[2];
#pragma unroll
    for (int c2 = 0; c2 < 2; c2++) bias2_4[c2] = *(const float4*)(b2 + c2 * 16 + kg * 4);

    for (int t = wid; t < ntiles; t += nw) {
        int r0 = t * 16;
        int row = min(r0 + col, n - 1);
        const ushort* xrow = xb + (size_t)row * NF;
        const ushort* arow = aggx + (size_t)row * NF;
        bf16x8 nfrag[4];             // B = node data, col = node
        nfrag[0] = *(const bf16x8*)(xrow + kg * 8);
        nfrag[1] = *(const bf16x8*)(xrow + 32 + kg * 8);
        nfrag[2] = *(const bf16x8*)(arow + kg * 8);
        nfrag[3] = *(const bf16x8*)(arow + 32 + kg * 8);

        int node = r0 + col;
        bool ok = node < n;
#pragma unroll
        for (int ct = 0; ct < 4; ct++) {
            f32x4 c = {0.f, 0.f, 0.f, 0.f};
#pragma unroll
            for (int kt = 0; kt < 4; kt++)
                c = __builtin_amdgcn_mfma_f32_16x16x32_bf16(wfrag[ct][kt], nfrag[kt], c, 0, 0, 0);
            uint2 pk;
            pk.x = (uint)f2bf(fmaxf(c[0] + bias4[ct].x, 0.f))
                 | ((uint)f2bf(fmaxf(c[1] + bias4[ct].y, 0.f)) << 16);
            pk.y = (uint)f2bf(fmaxf(c[2] + bias4[ct].z, 0.f))
                 | ((uint)f2bf(fmaxf(c[3] + bias4[ct].w, 0.f)) << 16);
            *(uint2*)(tile + col * 128 + ((ct * 32 + kg * 8) ^ sw)) = pk;
            if (ok) *(uint2*)(hb + (size_t)node * NF + ct * 16 + kg * 4) = pk;
        }

        // B-frags of hb from swizzled LDS (same-wave write->read, no barrier)
        bf16x8 hfrag[2];
        hfrag[0] = *(const bf16x8*)(tile + col * 128 + ((0 * 64 + kg * 16) ^ sw));
        hfrag[1] = *(const bf16x8*)(tile + col * 128 + ((1 * 64 + kg * 16) ^ sw));
#pragma unroll
        for (int c2 = 0; c2 < 2; c2++) {
            // un2 = hb @ Wn2^T (bf16)
            f32x4 c = {0.f, 0.f, 0.f, 0.f};
            c = __builtin_amdgcn_mfma_f32_16x16x32_bf16(wn2frag[c2][0], hfrag[0], c, 0, 0, 0);
            c = __builtin_amdgcn_mfma_f32_16x16x32_bf16(wn2frag[c2][1], hfrag[1], c, 0, 0, 0);
            // out self-term = hb @ Ws2^T + b2 (fp32)
            f32x4 s = {0.f, 0.f, 0.f, 0.f};
            s = __builtin_amdgcn_mfma_f32_16x16x32_bf16(ws2frag[c2][0], hfrag[0], s, 0, 0, 0);
            s = __builtin_amdgcn_mfma_f32_16x16x32_bf16(ws2frag[c2][1], hfrag[1], s, 0, 0, 0);
            if (ok) {
                uint2 pk;
                pk.x = (uint)f2bf(c[0]) | ((uint)f2bf(c[1]) << 16);
                pk.y = (uint)f2bf(c[2]) | ((uint)f2bf(c[3]) << 16);
                *(uint2*)(un2 + (size_t)node * OF + c2 * 16 + kg * 4) = pk;
                float4 o;
                o.x = s[0] + bias2_4[c2].x;
                o.y = s[1] + bias2_4[c2].y;
                o.z = s[2] + bias2_4[c2].z;
                o.w = s[3] + bias2_4[c2].w;
                *(float4*)(out + (size_t)node * OF + c2 * 16 + kg * 4) = o;
            }
        }
    }
}

// ---------------- launch ----------------

extern "C" void kernel_launch(void* const* d_in, const int* in_sizes, int n_in,
                              void* d_out, int out_size, void* d_ws, size_t ws_size,
                              hipStream_t stream) {
    const float* x   = (const float*)d_in[0];
    const int*   src = (const int*)d_in[1];
    const int*   dst = (const int*)d_in[2];
    const float* Ws1 = (const float*)d_in[3];
    const float* Wn1 = (const float*)d_in[4];
    const float* b1  = (const float*)d_in[5];
    const float* Ws2 = (const float*)d_in[6];
    const float* Wn2 = (const float*)d_in[7];
    const float* b2  = (const float*)d_in[8];
    float* out = (float*)d_out;

    int n_nodes = in_sizes[0] / NF;   // 100000
    int n_edges = in_sizes[1];        // 1600000
    int nb = (n_nodes + NPB - 1) >> NPB_SHIFT;   // 196 buckets

    // Workspace: gcur | row_ptr | csr | xb | hb | agg (aliases stage) | un2 | wt1 | wt2
    auto align4k = [](size_t v) { return (v + 4095) & ~(size_t)4095; };
    char* ws = (char*)d_ws;
    size_t gcur_b = align4k(256 * 4);
    size_t rp_b   = align4k(((size_t)n_nodes + 1) * 4);
    size_t csr_b  = align4k((size_t)n_edges * 4);
    size_t xb_b   = align4k((size_t)n_nodes * NF * 2);
    size_t hb_b   = xb_b;
    size_t agg_b  = xb_b;
    size_t un2_b  = align4k((size_t)n_nodes * OF * 2);
    int* gcur        = (int*)ws;
    int* row_ptr     = (int*)(ws + gcur_b);
    int* csr         = (int*)(ws + gcur_b + rp_b);
    ushort* xb       = (ushort*)(ws + gcur_b + rp_b + csr_b);
    ushort* hb       = (ushort*)(ws + gcur_b + rp_b + csr_b + xb_b);
    ushort* agg      = (ushort*)(ws + gcur_b + rp_b + csr_b + xb_b + hb_b);
    uint*   stage    = (uint*)agg;    // alias (dead before gather1 writes agg)
    ushort* un2      = (ushort*)(ws + gcur_b + rp_b + csr_b + xb_b + hb_b + agg_b);
    ushort* wt1      = (ushort*)(ws + gcur_b + rp_b + csr_b + xb_b + hb_b + agg_b + un2_b);
    ushort* wt2      = wt1 + NF * 128;

    int bin_blocks = (n_edges + BIN_CHUNK - 1) / BIN_CHUNK;   // 391
    int n4      = n_nodes * NF / 4;
    int cblocks = (n4 + 255) / 256;   // 6250
    int ntiles  = (n_nodes + 15) / 16;
    int mblocks = 512;     // gemm: 2048 waves, grid-stride over tiles

    zw_kernel<<<(NF * 128 + 255) / 256, 256, 0, stream>>>(Ws1, Wn1, Ws2, Wn2, wt1, wt2, gcur);
    convbin_kernel<<<cblocks + bin_blocks, 256, 0, stream>>>(x, xb, n4, cblocks,
                                                             src, dst, n_edges, gcur, stage);
    build_kernel<<<nb, 256, 0, stream>>>(stage, gcur, row_ptr, csr, n_nodes, nb);

    // Layer 1 + fused un2 (= hb@Wn2) + fused layer-2 self-term (out = hb@Ws2 + b2)
    gather_kernel<<<2048, 256, 0, stream>>>(xb, row_ptr, csr, agg, n_nodes);
    gemm1_fused_kernel<<<mblocks, 256, 0, stream>>>(xb, agg, wt1, wt2, b1, b2,
                                                    hb, un2, out, n_nodes, ntiles);

    // Layer 2 remainder: out += mean(un2[src]) in fp32
    gather_acc_kernel<<<1024, 256, 0, stream>>>(un2, row_ptr, csr, out, n_nodes);
}

// Round 19
// 113.779 us; speedup vs baseline: 1.0486x; 1.0486x over previous
//
#include <hip/hip_runtime.h>

#define NF 64     // IN == HID
#define OF 32     // OUT

#define NPB 512        // nodes per bucket (power of 2)
#define NPB_SHIFT 9
#define BCAP 12288     // max staged edges per bucket (mean 8192)
#define BIN_CHUNK 4096 // edges per binning block (256 thr x 16)

typedef unsigned int uint;
typedef unsigned short ushort;
typedef __attribute__((ext_vector_type(8))) short bf16x8;
typedef __attribute__((ext_vector_type(4))) float f32x4;

// ---------------- bf16 helpers ----------------

__device__ __forceinline__ ushort f2bf(float f) {
    uint u = __float_as_uint(f);
    uint r = (u + 0x7fffu + ((u >> 16) & 1u)) >> 16;   // RNE
    return (ushort)r;
}
__device__ __forceinline__ float bf2f(ushort b) { return __uint_as_float(((uint)b) << 16); }
__device__ __forceinline__ float blo(uint u) { return __uint_as_float(u << 16); }
__device__ __forceinline__ float bhi(uint u) { return __uint_as_float(u & 0xffff0000u); }

// ---------------- binning: LDS counting-sort, vectorized loads, coalesced stage writes ----

__global__ __launch_bounds__(256) void binning_kernel(
        const int* __restrict__ src, const int* __restrict__ dst, int n_edges,
        int* __restrict__ gcur, uint* __restrict__ stage) {
    __shared__ int hist[256];
    __shared__ int lofs[256];          // exclusive scan of hist
    __shared__ int gbase[256];         // global reservation per bucket
    __shared__ int lrank[256];
    __shared__ uint lsorted[BIN_CHUNK];
    __shared__ unsigned char lbkt[BIN_CHUNK];

    int t = threadIdx.x;
    hist[t] = 0;
    lrank[t] = 0;
    __syncthreads();

    int e0 = blockIdx.x * BIN_CHUNK;
    int base_e = e0 + t * 16;
    int nloc = min(16, max(0, n_edges - base_e));

    uint es[16], ed[16];
    if (nloc == 16) {
#pragma unroll
        for (int q = 0; q < 4; q++) {
            uint4 s4 = *(const uint4*)(src + base_e + q * 4);
            uint4 d4 = *(const uint4*)(dst + base_e + q * 4);
            es[q * 4 + 0] = s4.x; es[q * 4 + 1] = s4.y; es[q * 4 + 2] = s4.z; es[q * 4 + 3] = s4.w;
            ed[q * 4 + 0] = d4.x; ed[q * 4 + 1] = d4.y; ed[q * 4 + 2] = d4.z; ed[q * 4 + 3] = d4.w;
        }
    } else {
        for (int j = 0; j < nloc; j++) {
            es[j] = (uint)src[base_e + j];
            ed[j] = (uint)dst[base_e + j];
        }
    }

    for (int j = 0; j < nloc; j++)
        atomicAdd(&hist[ed[j] >> NPB_SHIFT], 1);
    __syncthreads();

    int hv = hist[t];
    lofs[t] = hv;
    __syncthreads();
    for (int off = 1; off < 256; off <<= 1) {
        int u = (t >= off) ? lofs[t - off] : 0;
        __syncthreads();
        lofs[t] += u;
        __syncthreads();
    }
    int incl = lofs[t];
    __syncthreads();
    lofs[t] = incl - hv;   // exclusive
    if (hv > 0) gbase[t] = atomicAdd(&gcur[t], hv);
    __syncthreads();

    for (int j = 0; j < nloc; j++) {
        int b = ed[j] >> NPB_SHIFT;
        int r = atomicAdd(&lrank[b], 1);
        int pos = lofs[b] + r;
        lsorted[pos] = ((ed[j] & (NPB - 1)) << 17) | es[j];
        lbkt[pos] = (unsigned char)b;
    }
    __syncthreads();

    int bcnt = min(BIN_CHUNK, n_edges - e0);
    for (int i = t; i < bcnt; i += 256) {
        int b = lbkt[i];
        int pos = gbase[b] + (i - lofs[b]);
        if (pos < BCAP) stage[(size_t)b * BCAP + pos] = lsorted[i];
    }
}

// build: one block per bucket. Inline exclusive scan of bucket counts (nb<=256),
// then per-node counts + scan in LDS -> row_ptr; scatter srcs in LDS; stream out.
__global__ __launch_bounds__(256) void build_kernel(
        const uint* __restrict__ stage, const int* __restrict__ gcnt,
        int* __restrict__ row_ptr, int* __restrict__ csr, int n, int nb) {
    __shared__ int bsc[256];
    __shared__ int ncnt[NPB];
    __shared__ int lcur[NPB];
    __shared__ int psum[256];
    __shared__ int lcsr[BCAP];

    int b = blockIdx.x;
    int t = threadIdx.x;

    bsc[t] = (t < nb) ? gcnt[t] : 0;
    __syncthreads();
    for (int off = 1; off < 256; off <<= 1) {
        int u = (t >= off) ? bsc[t - off] : 0;
        __syncthreads();
        bsc[t] += u;
        __syncthreads();
    }
    int gbase = (b == 0) ? 0 : bsc[b - 1];

    int cnt = min(gcnt[b], BCAP);
    int node0 = b << NPB_SHIFT;
    const uint* st = stage + (size_t)b * BCAP;

    ncnt[t] = 0;
    ncnt[t + 256] = 0;
    __syncthreads();
    for (int i = t; i < cnt; i += 256)
        atomicAdd(&ncnt[st[i] >> 17], 1);
    __syncthreads();

    int a0 = ncnt[2 * t], a1 = ncnt[2 * t + 1];
    psum[t] = a0 + a1;
    __syncthreads();
    for (int off = 1; off < 256; off <<= 1) {
        int u = (t >= off) ? psum[t - off] : 0;
        __syncthreads();
        psum[t] += u;
        __syncthreads();
    }
    int excl = (t == 0) ? 0 : psum[t - 1];
    int off0 = excl, off1 = excl + a0;
    int g0 = node0 + 2 * t, g1 = node0 + 2 * t + 1;
    if (g0 < n) row_ptr[g0] = gbase + off0;
    if (g1 < n) row_ptr[g1] = gbase + off1;
    lcur[2 * t] = off0;
    lcur[2 * t + 1] = off1;
    __syncthreads();

    for (int i = t; i < cnt; i += 256) {
        uint p = st[i];
        int slot = atomicAdd(&lcur[p >> 17], 1);
        lcsr[slot] = (int)(p & 0x1FFFFu);
    }
    __syncthreads();
    for (int i = t; i < cnt; i += 256)
        csr[gbase + i] = lcsr[i];

    if (b == nb - 1 && t == 0) row_ptr[n] = bsc[nb - 1];
}

// ---------------- convert x -> bf16, prep transposed bf16 weights, zero gcur ----------------

__global__ void convert_prep_kernel(const float* __restrict__ in, ushort* __restrict__ out, int n4,
                                    const float* __restrict__ Ws1, const float* __restrict__ Wn1,
                                    const float* __restrict__ Ws2, const float* __restrict__ Wn2,
                                    ushort* __restrict__ wt1, ushort* __restrict__ wt2,
                                    int* __restrict__ gcur) {
    int i = blockIdx.x * blockDim.x + threadIdx.x;
    if (blockIdx.x == 0) gcur[threadIdx.x] = 0;
    if (i < n4) {
        float4 v = *(const float4*)(in + (size_t)i * 4);
        ushort4 o;
        o.x = f2bf(v.x); o.y = f2bf(v.y); o.z = f2bf(v.z); o.w = f2bf(v.w);
        *(ushort4*)(out + (size_t)i * 4) = o;
    }
    if (i < NF * 128) {        // wt1: 64 cols x 128 k
        int c = i >> 7, k = i & 127;
        float v = (k < 64) ? Ws1[k * NF + c] : Wn1[(k - 64) * NF + c];
        wt1[i] = f2bf(v);
    }
    if (i < OF * 128) {        // wt2: 32 cols x 128 k (k<64: Ws2, k>=64: Wn2)
        int c = i >> 7, k = i & 127;
        float v = (k < 64) ? Ws2[k * OF + c] : Wn2[(k - 64) * OF + c];
        wt2[i] = f2bf(v);
    }
}

// ---------------- gather (layer 1): uint4 (16B/lane), full/tail split, 8-deep pipeline ----

__global__ __launch_bounds__(256) void gather_kernel(
        const ushort* __restrict__ feat,
        const int* __restrict__ row_ptr, const int* __restrict__ csr,
        ushort* __restrict__ agg, int n) {
    constexpr int LPG = NF / 8;
    constexpr int NPW = 64 / LPG;
    int lane = threadIdx.x & 63;
    int g = lane / LPG;
    int fo = (lane % LPG) * 8;
    int wave = blockIdx.x * 4 + (threadIdx.x >> 6);
    int stride = gridDim.x * 4 * NPW;

    for (int n0 = wave * NPW + g; n0 < n; n0 += stride) {
        int beg = row_ptr[n0], end = row_ptr[n0 + 1];
        int cnt = end - beg;
        int full = beg + (cnt & ~7);
        float a0 = 0.f, a1 = 0.f, a2 = 0.f, a3 = 0.f;
        float a4 = 0.f, a5 = 0.f, a6 = 0.f, a7 = 0.f;
        for (int o = beg; o < full; o += 8) {
            uint4 v[8];
#pragma unroll
            for (int j = 0; j < 8; j++)
                v[j] = *(const uint4*)(feat + (size_t)csr[o + j] * NF + fo);
#pragma unroll
            for (int j = 0; j < 8; j++) {
                a0 += blo(v[j].x); a1 += bhi(v[j].x);
                a2 += blo(v[j].y); a3 += bhi(v[j].y);
                a4 += blo(v[j].z); a5 += bhi(v[j].z);
                a6 += blo(v[j].w); a7 += bhi(v[j].w);
            }
        }
        if (full < end) {
            uint4 v[8];
#pragma unroll
            for (int j = 0; j < 8; j++) {
                int e = min(full + j, end - 1);
                v[j] = *(const uint4*)(feat + (size_t)csr[e] * NF + fo);
            }
#pragma unroll
            for (int j = 0; j < 8; j++) {
                bool ok = (full + j) < end;
                uint vx = ok ? v[j].x : 0u, vy = ok ? v[j].y : 0u;
                uint vz = ok ? v[j].z : 0u, vw = ok ? v[j].w : 0u;
                a0 += blo(vx); a1 += bhi(vx);
                a2 += blo(vy); a3 += bhi(vy);
                a4 += blo(vz); a5 += bhi(vz);
                a6 += blo(vw); a7 += bhi(vw);
            }
        }
        float inv = 1.0f / (float)max(cnt, 1);
        uint4 o4;
        o4.x = (uint)f2bf(a0 * inv) | ((uint)f2bf(a1 * inv) << 16);
        o4.y = (uint)f2bf(a2 * inv) | ((uint)f2bf(a3 * inv) << 16);
        o4.z = (uint)f2bf(a4 * inv) | ((uint)f2bf(a5 * inv) << 16);
        o4.w = (uint)f2bf(a6 * inv) | ((uint)f2bf(a7 * inv) << 16);
        *(uint4*)(agg + (size_t)n0 * NF + fo) = o4;
    }
}

// ---------------- gather_acc (layer 2): out[node] += mean(un2[src]) in fp32 ----------------

__global__ __launch_bounds__(256) void gather_acc_kernel(
        const ushort* __restrict__ un2,
        const int* __restrict__ row_ptr, const int* __restrict__ csr,
        float* __restrict__ out, int n) {
    constexpr int LPG = OF / 8;
    constexpr int NPW = 64 / LPG;
    int lane = threadIdx.x & 63;
    int g = lane / LPG;
    int fo = (lane % LPG) * 8;
    int wave = blockIdx.x * 4 + (threadIdx.x >> 6);
    int stride = gridDim.x * 4 * NPW;

    for (int n0 = wave * NPW + g; n0 < n; n0 += stride) {
        int beg = row_ptr[n0], end = row_ptr[n0 + 1];
        int cnt = end - beg;
        int full = beg + (cnt & ~7);
        float a0 = 0.f, a1 = 0.f, a2 = 0.f, a3 = 0.f;
        float a4 = 0.f, a5 = 0.f, a6 = 0.f, a7 = 0.f;
        for (int o = beg; o < full; o += 8) {
            uint4 v[8];
#pragma unroll
            for (int j = 0; j < 8; j++)
                v[j] = *(const uint4*)(un2 + (size_t)csr[o + j] * OF + fo);
#pragma unroll
            for (int j = 0; j < 8; j++) {
                a0 += blo(v[j].x); a1 += bhi(v[j].x);
                a2 += blo(v[j].y); a3 += bhi(v[j].y);
                a4 += blo(v[j].z); a5 += bhi(v[j].z);
                a6 += blo(v[j].w); a7 += bhi(v[j].w);
            }
        }
        if (full < end) {
            uint4 v[8];
#pragma unroll
            for (int j = 0; j < 8; j++) {
                int e = min(full + j, end - 1);
                v[j] = *(const uint4*)(un2 + (size_t)csr[e] * OF + fo);
            }
#pragma unroll
            for (int j = 0; j < 8; j++) {
                bool ok = (full + j) < end;
                uint vx = ok ? v[j].x : 0u, vy = ok ? v[j].y : 0u;
                uint vz = ok ? v[j].z : 0u, vw = ok ? v[j].w : 0u;
                a0 += blo(vx); a1 += bhi(vx);
                a2 += blo(vy); a3 += bhi(vy);
                a4 += blo(vz); a5 += bhi(vz);
                a6 += blo(vw); a7 += bhi(vw);
            }
        }
        float inv = 1.0f / (float)max(cnt, 1);
        float* op = out + (size_t)n0 * OF + fo;
        float4 o0 = *(const float4*)op;
        float4 o1 = *(const float4*)(op + 4);
        o0.x += a0 * inv; o0.y += a1 * inv; o0.z += a2 * inv; o0.w += a3 * inv;
        o1.x += a4 * inv; o1.y += a5 * inv; o1.z += a6 * inv; o1.w += a7 * inv;
        *(float4*)op = o0;
        *(float4*)(op + 4) = o1;
    }
}

// ---------------- gemm1_fused: hb = bf16(relu([xb|aggx]@Wt1^T + b1));
//                  un2 = bf16(hb@Wn2^T); out = hb@Ws2^T + b2 (fp32 self-term) ----------------
// SWAPPED operands: A = weights (row = out feature), B = node data (col = node).

__global__ __launch_bounds__(256) void gemm1_fused_kernel(
        const ushort* __restrict__ xb, const ushort* __restrict__ aggx,
        const ushort* __restrict__ wt1,  // [64][128]
        const ushort* __restrict__ wt2,  // [32][128] (k<64 = Ws2, k>=64 = Wn2)
        const float* __restrict__ b1,    // [64]
        const float* __restrict__ b2,    // [32]
        ushort* __restrict__ hb, ushort* __restrict__ un2,
        float* __restrict__ out, int n, int ntiles) {
    __shared__ char tiles[4][2048];
    int lane = threadIdx.x & 63;
    int wslot = threadIdx.x >> 6;
    char* tile = tiles[wslot];
    int col = lane & 15, kg = lane >> 4;
    int wid = blockIdx.x * 4 + wslot;
    int nw = gridDim.x * 4;
    int sw = (col & 7) << 4;

    bf16x8 wfrag[4][4];              // A = Wt1
#pragma unroll
    for (int ct = 0; ct < 4; ct++)
#pragma unroll
        for (int kt = 0; kt < 4; kt++)
            wfrag[ct][kt] = *(const bf16x8*)(wt1 + ((ct * 16 + col) * 128 + kt * 32 + kg * 8));
    bf16x8 wn2frag[2][2];            // A = Wn2 (k>=64 half of wt2)
    bf16x8 ws2frag[2][2];            // A = Ws2 (k<64 half of wt2)
#pragma unroll
    for (int c2 = 0; c2 < 2; c2++)
#pragma unroll
        for (int kt = 0; kt < 2; kt++) {
            wn2frag[c2][kt] = *(const bf16x8*)(wt2 + ((c2 * 16 + col) * 128 + 64 + kt * 32 + kg * 8));
            ws2frag[c2][kt] = *(const bf16x8*)(wt2 + ((c2 * 16 + col) * 128 + kt * 32 + kg * 8));
        }
    float4 bias4[4];
#pragma unroll
    for (int ct = 0; ct < 4; ct++) bias4[ct] = *(const float4*)(b1 + ct * 16 + kg * 4);
    float4 bias2_4[2];
#pragma unroll
    for (int c2 = 0; c2 < 2; c2++) bias2_4[c2] = *(const float4*)(b2 + c2 * 16 + kg * 4);

    for (int t = wid; t < ntiles; t += nw) {
        int r0 = t * 16;
        int row = min(r0 + col, n - 1);
        const ushort* xrow = xb + (size_t)row * NF;
        const ushort* arow = aggx + (size_t)row * NF;
        bf16x8 nfrag[4];             // B = node data, col = node
        nfrag[0] = *(const bf16x8*)(xrow + kg * 8);
        nfrag[1] = *(const bf16x8*)(xrow + 32 + kg * 8);
        nfrag[2] = *(const bf16x8*)(arow + kg * 8);
        nfrag[3] = *(const bf16x8*)(arow + 32 + kg * 8);

        int node = r0 + col;
        bool ok = node < n;
#pragma unroll
        for (int ct = 0; ct < 4; ct++) {
            f32x4 c = {0.f, 0.f, 0.f, 0.f};
#pragma unroll
            for (int kt = 0; kt < 4; kt++)
                c = __builtin_amdgcn_mfma_f32_16x16x32_bf16(wfrag[ct][kt], nfrag[kt], c, 0, 0, 0);
            uint2 pk;
            pk.x = (uint)f2bf(fmaxf(c[0] + bias4[ct].x, 0.f))
                 | ((uint)f2bf(fmaxf(c[1] + bias4[ct].y, 0.f)) << 16);
            pk.y = (uint)f2bf(fmaxf(c[2] + bias4[ct].z, 0.f))
                 | ((uint)f2bf(fmaxf(c[3] + bias4[ct].w, 0.f)) << 16);
            *(uint2*)(tile + col * 128 + ((ct * 32 + kg * 8) ^ sw)) = pk;
            if (ok) *(uint2*)(hb + (size_t)node * NF + ct * 16 + kg * 4) = pk;
        }

        // B-frags of hb from swizzled LDS (same-wave write->read, no barrier)
        bf16x8 hfrag[2];
        hfrag[0] = *(const bf16x8*)(tile + col * 128 + ((0 * 64 + kg * 16) ^ sw));
        hfrag[1] = *(const bf16x8*)(tile + col * 128 + ((1 * 64 + kg * 16) ^ sw));
#pragma unroll
        for (int c2 = 0; c2 < 2; c2++) {
            // un2 = hb @ Wn2^T (bf16)
            f32x4 c = {0.f, 0.f, 0.f, 0.f};
            c = __builtin_amdgcn_mfma_f32_16x16x32_bf16(wn2frag[c2][0], hfrag[0], c, 0, 0, 0);
            c = __builtin_amdgcn_mfma_f32_16x16x32_bf16(wn2frag[c2][1], hfrag[1], c, 0, 0, 0);
            // out self-term = hb @ Ws2^T + b2 (fp32)
            f32x4 s = {0.f, 0.f, 0.f, 0.f};
            s = __builtin_amdgcn_mfma_f32_16x16x32_bf16(ws2frag[c2][0], hfrag[0], s, 0, 0, 0);
            s = __builtin_amdgcn_mfma_f32_16x16x32_bf16(ws2frag[c2][1], hfrag[1], s, 0, 0, 0);
            if (ok) {
                uint2 pk;
                pk.x = (uint)f2bf(c[0]) | ((uint)f2bf(c[1]) << 16);
                pk.y = (uint)f2bf(c[2]) | ((uint)f2bf(c[3]) << 16);
                *(uint2*)(un2 + (size_t)node * OF + c2 * 16 + kg * 4) = pk;
                float4 o;
                o.x = s[0] + bias2_4[c2].x;
                o.y = s[1] + bias2_4[c2].y;
                o.z = s[2] + bias2_4[c2].z;
                o.w = s[3] + bias2_4[c2].w;
                *(float4*)(out + (size_t)node * OF + c2 * 16 + kg * 4) = o;
            }
        }
    }
}

// ---------------- launch ----------------

extern "C" void kernel_launch(void* const* d_in, const int* in_sizes, int n_in,
                              void* d_out, int out_size, void* d_ws, size_t ws_size,
                              hipStream_t stream) {
    const float* x   = (const float*)d_in[0];
    const int*   src = (const int*)d_in[1];
    const int*   dst = (const int*)d_in[2];
    const float* Ws1 = (const float*)d_in[3];
    const float* Wn1 = (const float*)d_in[4];
    const float* b1  = (const float*)d_in[5];
    const float* Ws2 = (const float*)d_in[6];
    const float* Wn2 = (const float*)d_in[7];
    const float* b2  = (const float*)d_in[8];
    float* out = (float*)d_out;

    int n_nodes = in_sizes[0] / NF;   // 100000
    int n_edges = in_sizes[1];        // 1600000
    int nb = (n_nodes + NPB - 1) >> NPB_SHIFT;   // 196 buckets

    // Workspace: gcur | row_ptr | csr | xb | hb | agg (aliases stage) | un2 | wt1 | wt2
    auto align4k = [](size_t v) { return (v + 4095) & ~(size_t)4095; };
    char* ws = (char*)d_ws;
    size_t gcur_b = align4k(256 * 4);
    size_t rp_b   = align4k(((size_t)n_nodes + 1) * 4);
    size_t csr_b  = align4k((size_t)n_edges * 4);
    size_t xb_b   = align4k((size_t)n_nodes * NF * 2);
    size_t hb_b   = xb_b;
    size_t agg_b  = xb_b;
    size_t un2_b  = align4k((size_t)n_nodes * OF * 2);
    int* gcur        = (int*)ws;
    int* row_ptr     = (int*)(ws + gcur_b);
    int* csr         = (int*)(ws + gcur_b + rp_b);
    ushort* xb       = (ushort*)(ws + gcur_b + rp_b + csr_b);
    ushort* hb       = (ushort*)(ws + gcur_b + rp_b + csr_b + xb_b);
    ushort* agg      = (ushort*)(ws + gcur_b + rp_b + csr_b + xb_b + hb_b);
    uint*   stage    = (uint*)agg;    // alias (dead before gather1 writes agg)
    ushort* un2      = (ushort*)(ws + gcur_b + rp_b + csr_b + xb_b + hb_b + agg_b);
    ushort* wt1      = (ushort*)(ws + gcur_b + rp_b + csr_b + xb_b + hb_b + agg_b + un2_b);
    ushort* wt2      = wt1 + NF * 128;

    int bin_blocks = (n_edges + BIN_CHUNK - 1) / BIN_CHUNK;   // 391
    int n4      = n_nodes * NF / 4;
    int cblocks = (n4 + 255) / 256;
    int ntiles  = (n_nodes + 15) / 16;
    int mblocks = 512;     // gemm: 2048 waves, grid-stride over tiles

    convert_prep_kernel<<<cblocks, 256, 0, stream>>>(x, xb, n4, Ws1, Wn1, Ws2, Wn2, wt1, wt2, gcur);
    binning_kernel<<<bin_blocks, 256, 0, stream>>>(src, dst, n_edges, gcur, stage);
    build_kernel<<<nb, 256, 0, stream>>>(stage, gcur, row_ptr, csr, n_nodes, nb);

    // Layer 1 + fused un2 (= hb@Wn2) + fused layer-2 self-term (out = hb@Ws2 + b2)
    gather_kernel<<<2048, 256, 0, stream>>>(xb, row_ptr, csr, agg, n_nodes);
    gemm1_fused_kernel<<<mblocks, 256, 0, stream>>>(xb, agg, wt1, wt2, b1, b2,
                                                    hb, un2, out, n_nodes, ntiles);

    // Layer 2 remainder: out += mean(un2[src]) in fp32
    gather_acc_kernel<<<1024, 256, 0, stream>>>(un2, row_ptr, csr, out, n_nodes);
}